// Round 12
// baseline (485.886 us; speedup 1.0000x reference)
//
#include <hip/hip_runtime.h>
#include <hip/hip_bf16.h>
#include <hip/hip_fp16.h>
#include <math.h>

#define NN 50000
#define NE 800000

typedef __attribute__((ext_vector_type(8))) short bf16x8;
typedef __attribute__((ext_vector_type(4))) float f32x4;

__device__ __forceinline__ short f2bf(float f){
  unsigned u = __float_as_uint(f);
  unsigned r = (u + 0x7fffu + ((u >> 16) & 1u)) >> 16;
  return (short)r;
}
__device__ __forceinline__ float bf2f(short s){
  return __uint_as_float(((unsigned)(unsigned short)s) << 16);
}

// ---- fp8 e4m3 via exact f16 scaling: e4m3(v) == f16bits(v*2^-8) >> 7 (sign separate) ----
__device__ __forceinline__ unsigned f2fp8(float f){
  __half h = __float2half(f * 0.00390625f);          // v * 2^-8, RNE
  unsigned hb = (unsigned)__half_as_ushort(h);
  unsigned s = hb >> 15;
  unsigned mag = hb & 0x7fffu;
  mag = mag + 0x3fu + ((mag >> 7) & 1u);             // RNE drop of low 7 bits
  unsigned m8 = mag >> 7;
  if (m8 > 0x7eu) m8 = 0x7eu;                        // clamp below NaN encoding
  return (s << 7) | m8;
}
// decode 4 fp8 (packed LE in u) -> 4 floats scaled by 2^-8
__device__ __forceinline__ void fp8x4_dec(unsigned u, float2& lo, float2& hi){
  unsigned l = ((u & 0x80u) << 8) | ((u & 0x7fu) << 7)
             | ((u & 0x8000u) << 16) | ((u & 0x7f00u) << 15);
  unsigned h = ((u & 0x800000u) >> 8) | ((u & 0x7f0000u) >> 9)
             | (u & 0x80000000u) | ((u & 0x7f000000u) >> 1);
  __half2 hl = *(__half2*)&l;
  __half2 hh = *(__half2*)&h;
  lo = __half22float2(hl);
  hi = __half22float2(hh);
}
// dot of 4 fp8 pairs; result scaled by 2^-16
__device__ __forceinline__ float fp8_dot4(unsigned a, unsigned b){
  float2 al, ah, bl, bh;
  fp8x4_dec(a, al, ah); fp8x4_dec(b, bl, bh);
  return al.x*bl.x + al.y*bl.y + ah.x*bh.x + ah.y*bh.y;
}

// ---------------- zero cnt + stat scalars ----------------
__global__ __launch_bounds__(256) void zero_cnt_k(int* __restrict__ cnt, float* __restrict__ scal, int n){
  int i = blockIdx.x*256 + threadIdx.x;
  if (i < n) cnt[i] = 0;
  if (blockIdx.x == 0 && threadIdx.x < 16) scal[threadIdx.x] = 0.0f;
}

// ---------------- weight prep: transpose + bf16 convert (MLP + GCN weights) ----------------
__global__ __launch_bounds__(256) void prep_k(const float* __restrict__ w1,
    const float* __restrict__ w2, const float* __restrict__ w3, const float* __restrict__ pars,
    const float* __restrict__ lin0w, const float* __restrict__ cw1, const float* __restrict__ lin1w,
    short* __restrict__ w1t, short* __restrict__ w2t, short* __restrict__ w3t, short* __restrict__ Pt,
    short* __restrict__ lin0wt, short* __restrict__ cw1t0, short* __restrict__ cw1t1,
    short* __restrict__ lin1wt){
  int idx = blockIdx.x*256 + threadIdx.x;
  if (idx < 65536){
    int n = idx >> 7, k = idx & 127;
    w1t[idx] = f2bf(w1[k*512 + n]);
  } else if (idx < 98304){
    int i = idx - 65536; int n = i >> 9, k = i & 511;
    w2t[i] = f2bf(w2[k*64 + n]);
  } else if (idx < 102400){
    int i = idx - 98304; int n = i >> 6, k = i & 63;
    w3t[i] = f2bf(w3[k*64 + n]);
  } else if (idx < 106496){
    int i = idx - 102400; int n = i >> 6, k = i & 63;
    Pt[i] = f2bf(fmaxf(2.f*pars[k*64 + n], 0.f));
  } else if (idx < 122880){
    int i = idx - 106496; int n = i >> 7, k = i & 127;
    lin0wt[i] = f2bf(lin0w[k*128 + n]);
  } else if (idx < 139264){
    int i = idx - 122880; int n = i >> 7, k = i & 127;
    cw1t0[i] = f2bf(cw1[k*128 + n]);
  } else if (idx < 155648){
    int i = idx - 139264; int n = i >> 7, k = i & 127;
    cw1t1[i] = f2bf(cw1[16384 + k*128 + n]);
  } else if (idx < 163840){
    int i = idx - 155648; int n = i >> 7, k = i & 127;   // n in [0,64)
    lin1wt[i] = f2bf(lin1w[k*64 + n]);
  }
}

// ---------------- fused bf16-MFMA MLP chain, 16 rows/block -> fp8 logits/logitsP (+ xb) ----------------
// 16 rows: LDS 25.6 KB -> 6 blocks/CU (was 51.2 KB -> 3); phase acc registers halved.
__global__ __launch_bounds__(256) void mlp_mfma_k(
    const float* __restrict__ x,
    const short* __restrict__ w1t, const float* __restrict__ b1,
    const short* __restrict__ w2t, const float* __restrict__ b2,
    const short* __restrict__ w3t, const float* __restrict__ b3,
    const short* __restrict__ Pt,
    unsigned char* __restrict__ lg8, unsigned char* __restrict__ lgp8,
    short* __restrict__ xb, int M)
{
  __shared__ short xs [16][136];
  __shared__ short h1s[16][520];
  __shared__ short h2s[16][72];   // phase2 out; reused as logitsP staging in phase 4
  __shared__ short lgs[16][72];
  const int t = threadIdx.x;
  const int wave = t >> 6, lane = t & 63;
  const int quad = lane >> 4, l16 = lane & 15;
  const int m0 = blockIdx.x * 16;

  // stage x (16 rows x 128) -> bf16 LDS; one task per thread
  {
    int row = t >> 4, c0 = (t & 15) * 8;
    float4 v0 = make_float4(0,0,0,0), v1 = v0;
    if (m0 + row < M){
      v0 = *(const float4*)(x + (size_t)(m0+row)*128 + c0);
      v1 = *(const float4*)(x + (size_t)(m0+row)*128 + c0 + 4);
    }
    bf16x8 s;
    s[0]=f2bf(v0.x); s[1]=f2bf(v0.y); s[2]=f2bf(v0.z); s[3]=f2bf(v0.w);
    s[4]=f2bf(v1.x); s[5]=f2bf(v1.y); s[6]=f2bf(v1.z); s[7]=f2bf(v1.w);
    *(bf16x8*)&xs[row][c0] = s;
  }
  __syncthreads();

  // ---- Phase 1: h1 = relu(x @ w1 + b1); wave -> cols [wave*128, +128) ----
  {
    f32x4 acc[8];
    #pragma unroll
    for (int nt=0;nt<8;nt++) acc[nt] = (f32x4){0.f,0.f,0.f,0.f};
    for (int k0 = 0; k0 < 128; k0 += 32){
      bf16x8 a0 = *(const bf16x8*)&xs[l16][k0 + quad*8];
      #pragma unroll
      for (int nt = 0; nt < 8; nt++){
        int n = wave*128 + nt*16 + l16;
        bf16x8 b = *(const bf16x8*)(w1t + (size_t)n*128 + k0 + quad*8);
        acc[nt] = __builtin_amdgcn_mfma_f32_16x16x32_bf16(a0, b, acc[nt], 0,0,0);
      }
    }
    #pragma unroll
    for (int nt = 0; nt < 8; nt++){
      int n = wave*128 + nt*16 + l16;
      float bb = b1[n];
      #pragma unroll
      for (int r = 0; r < 4; r++)
        h1s[quad*4 + r][n] = f2bf(fmaxf(acc[nt][r] + bb, 0.f));
    }
  }
  __syncthreads();

  // ---- Phase 2: h2 = relu(h1 @ w2 + b2); wave -> cols [wave*16, +16) ----
  {
    f32x4 acc = (f32x4){0.f,0.f,0.f,0.f};
    const int n = wave*16 + l16;
    for (int k0 = 0; k0 < 512; k0 += 32){
      bf16x8 b  = *(const bf16x8*)(w2t + (size_t)n*512 + k0 + quad*8);
      bf16x8 a0 = *(const bf16x8*)&h1s[l16][k0 + quad*8];
      acc = __builtin_amdgcn_mfma_f32_16x16x32_bf16(a0, b, acc, 0,0,0);
    }
    float bb = b2[n];
    #pragma unroll
    for (int r = 0; r < 4; r++)
      h2s[quad*4 + r][n] = f2bf(fmaxf(acc[r] + bb, 0.f));
  }
  __syncthreads();

  // ---- Phase 3: logits = h2 @ w3 + b3 -> lgs ----
  {
    f32x4 acc = (f32x4){0.f,0.f,0.f,0.f};
    const int n = wave*16 + l16;
    for (int k0 = 0; k0 < 64; k0 += 32){
      bf16x8 b  = *(const bf16x8*)(w3t + (size_t)n*64 + k0 + quad*8);
      bf16x8 a0 = *(const bf16x8*)&h2s[l16][k0 + quad*8];
      acc = __builtin_amdgcn_mfma_f32_16x16x32_bf16(a0, b, acc, 0,0,0);
    }
    float bb = b3[n];
    #pragma unroll
    for (int r = 0; r < 4; r++)
      lgs[quad*4 + r][n] = f2bf(acc[r] + bb);
  }
  __syncthreads();

  // ---- Phase 4: logitsP = logits @ relu(2P) -> h2s ----
  {
    f32x4 acc = (f32x4){0.f,0.f,0.f,0.f};
    const int n = wave*16 + l16;
    for (int k0 = 0; k0 < 64; k0 += 32){
      bf16x8 b  = *(const bf16x8*)(Pt + (size_t)n*64 + k0 + quad*8);
      bf16x8 a0 = *(const bf16x8*)&lgs[l16][k0 + quad*8];
      acc = __builtin_amdgcn_mfma_f32_16x16x32_bf16(a0, b, acc, 0,0,0);
    }
    #pragma unroll
    for (int r = 0; r < 4; r++)
      h2s[quad*4 + r][n] = f2bf(acc[r]);
  }
  __syncthreads();

  // ---- cooperative store: lgs -> lg8 (fp8), h2s -> lgp8 (fp8); 128 tasks ----
  if (t < 128){
    int row = t >> 3, c0 = (t & 7) * 8;
    int gm = m0 + row;
    if (gm < M){
      const short* pl = &lgs[row][c0];
      const short* pp = &h2s[row][c0];
      unsigned a0 = 0, a1 = 0, b0 = 0, b1 = 0;
      #pragma unroll
      for (int j = 0; j < 4; j++){
        a0 |= f2fp8(bf2f(pl[j]))     << (8*j);
        a1 |= f2fp8(bf2f(pl[4+j]))   << (8*j);
        b0 |= f2fp8(bf2f(pp[j]))     << (8*j);
        b1 |= f2fp8(bf2f(pp[4+j]))   << (8*j);
      }
      uint2 av; av.x = a0; av.y = a1;
      uint2 bv; bv.x = b0; bv.y = b1;
      *(uint2*)(lg8  + (size_t)gm*64 + c0) = av;
      *(uint2*)(lgp8 + (size_t)gm*64 + c0) = bv;
    }
  }
  // dump staged bf16 x -> xb (feeds x0 GEMM); one task per thread
  {
    int row = t >> 4, c0 = (t & 15) * 8;
    int gm = m0 + row;
    if (gm < M)
      *(bf16x8*)(xb + (size_t)gm*128 + c0) = *(const bf16x8*)&xs[row][c0];
  }
}

// ---------------- bf16 MFMA GEMM: C[M][N] = EPI(A[M][128] @ Bt[N][128]^T) ----------------
template<int NT, bool RELU, bool RESID, bool BF16OUT>
__global__ __launch_bounds__(256) void bgemm_k(
    const short* __restrict__ A, const short* __restrict__ Bt,
    const float* __restrict__ bias, const short* __restrict__ extra,
    float* __restrict__ C, short* __restrict__ Cb, int M, float beta)
{
  const int N = NT*64;
  __shared__ short As[32][136];
  const int t = threadIdx.x;
  const int wave = t >> 6, lane = t & 63;
  const int quad = lane >> 4, l16 = lane & 15;
  const int m0 = blockIdx.x * 32;

  for (int task = t; task < 512; task += 256){
    int row = task >> 4, c0 = (task & 15) * 8;
    bf16x8 v = {0,0,0,0,0,0,0,0};
    if (m0 + row < M) v = *(const bf16x8*)(A + (size_t)(m0+row)*128 + c0);
    *(bf16x8*)&As[row][c0] = v;
  }
  __syncthreads();

  f32x4 acc[2][NT];
  #pragma unroll
  for (int mt=0;mt<2;mt++)
    #pragma unroll
    for (int nt=0;nt<NT;nt++) acc[mt][nt] = (f32x4){0.f,0.f,0.f,0.f};

  #pragma unroll
  for (int k0 = 0; k0 < 128; k0 += 32){
    bf16x8 a0 = *(const bf16x8*)&As[l16     ][k0 + quad*8];
    bf16x8 a1 = *(const bf16x8*)&As[16 + l16][k0 + quad*8];
    #pragma unroll
    for (int nt = 0; nt < NT; nt++){
      int n = (wave*NT + nt)*16 + l16;
      bf16x8 b = *(const bf16x8*)(Bt + (size_t)n*128 + k0 + quad*8);
      acc[0][nt] = __builtin_amdgcn_mfma_f32_16x16x32_bf16(a0, b, acc[0][nt], 0,0,0);
      acc[1][nt] = __builtin_amdgcn_mfma_f32_16x16x32_bf16(a1, b, acc[1][nt], 0,0,0);
    }
  }

  #pragma unroll
  for (int nt = 0; nt < NT; nt++){
    int n = (wave*NT + nt)*16 + l16;
    float bb = (bias != nullptr) ? bias[n] : 0.f;
    #pragma unroll
    for (int mt = 0; mt < 2; mt++){
      #pragma unroll
      for (int r = 0; r < 4; r++){
        int gm = m0 + mt*16 + quad*4 + r;
        if (gm >= M) continue;
        float v = acc[mt][nt][r];
        if (RESID){
          float ex = bf2f(extra[(size_t)gm*N + n]);
          v = beta*v + (1.f - beta)*ex;
        }
        v += bb;
        if (RELU) v = fmaxf(v, 0.f);
        if (BF16OUT) Cb[(size_t)gm*N + n] = f2bf(v);
        else         C [(size_t)gm*N + n] = v;
      }
    }
  }
}

// ---------------- count in-degree (int) at col ----------------
__global__ __launch_bounds__(256) void count_k(const int* __restrict__ col, int* __restrict__ cnt, int E){
  int e = blockIdx.x*256 + threadIdx.x;
  if (e < E) atomicAdd(&cnt[col[e]], 1);
}

// ---------------- multi-block exclusive scan (3 phases) ----------------
__global__ __launch_bounds__(256) void scan_sums_k(const int* __restrict__ cnt, int* __restrict__ bsum, int n){
  __shared__ int s[256];
  const int t = threadIdx.x;
  int i = blockIdx.x*1024 + t*4;
  int4 v = make_int4(0,0,0,0);
  if (i + 3 < n) v = *(const int4*)(cnt + i);
  else {
    if (i   < n) v.x = cnt[i];
    if (i+1 < n) v.y = cnt[i+1];
    if (i+2 < n) v.z = cnt[i+2];
    if (i+3 < n) v.w = cnt[i+3];
  }
  s[t] = v.x + v.y + v.z + v.w;
  __syncthreads();
  for (int st = 128; st; st >>= 1){
    if (t < st) s[t] += s[t + st];
    __syncthreads();
  }
  if (t == 0) bsum[blockIdx.x] = s[0];
}

__global__ __launch_bounds__(64) void scan_bsum_k(int* __restrict__ bsum, int nb){
  int t = threadIdx.x;
  int own = (t < nb) ? bsum[t] : 0;
  int v = own;
  #pragma unroll
  for (int off = 1; off < 64; off <<= 1){
    int o = __shfl_up(v, off, 64);
    if (t >= off) v += o;
  }
  if (t < nb) bsum[t] = v - own;   // exclusive
}

__global__ __launch_bounds__(256) void scan_final_k(const int* __restrict__ cnt, const int* __restrict__ bsum,
    int* __restrict__ off, int* __restrict__ cursor, int n, int total){
  __shared__ int s[256];
  const int t = threadIdx.x;
  int i = blockIdx.x*1024 + t*4;
  int4 v = make_int4(0,0,0,0);
  if (i + 3 < n) v = *(const int4*)(cnt + i);
  else {
    if (i   < n) v.x = cnt[i];
    if (i+1 < n) v.y = cnt[i+1];
    if (i+2 < n) v.z = cnt[i+2];
    if (i+3 < n) v.w = cnt[i+3];
  }
  int tsum = v.x + v.y + v.z + v.w;
  s[t] = tsum;
  __syncthreads();
  #pragma unroll
  for (int st = 1; st < 256; st <<= 1){
    int a = (t >= st) ? s[t - st] : 0;
    __syncthreads();
    s[t] += a;
    __syncthreads();
  }
  int base = s[t] - tsum + bsum[blockIdx.x];
  int o0 = base, o1 = o0 + v.x, o2 = o1 + v.y, o3 = o2 + v.z;
  if (i   < n){ off[i]   = o0; cursor[i]   = o0; }
  if (i+1 < n){ off[i+1] = o1; cursor[i+1] = o1; }
  if (i+2 < n){ off[i+2] = o2; cursor[i+2] = o2; }
  if (i+3 < n){ off[i+3] = o3; cursor[i+3] = o3; }
  if (blockIdx.x == 0 && t == 0) off[n] = total;
}

// bucket edges by destination; store src AND dst per slot
__global__ __launch_bounds__(256) void scatter_k(const int* __restrict__ row, const int* __restrict__ col,
    int* __restrict__ cursor, int* __restrict__ csr_src, int* __restrict__ csr_dst, int E){
  int e = blockIdx.x*256 + threadIdx.x;
  if (e < E){
    int r = row[e], c = col[e];
    int slot = atomicAdd(&cursor[c], 1);
    csr_src[slot] = r;
    csr_dst[slot] = c;
  }
}

// ---------------- ew over CSR slots: 16-lane groups, explicit 4-edge batch pipeline ----------------
__global__ __launch_bounds__(256) void ew2_k(const unsigned char* __restrict__ lg8,
    const unsigned char* __restrict__ lgp8,
    const int* __restrict__ src, const int* __restrict__ dst,
    float* __restrict__ w, float* __restrict__ scal, int E){
  const int t = threadIdx.x;
  const int lane = t & 63, wid = t >> 6;
  const int g = lane >> 4, q = lane & 15;
  const int gid = (blockIdx.x*4 + wid)*4 + g;     // global 16-lane group id
  const int ngroups = gridDim.x*16;
  float s = 0.f, ss = 0.f;
  for (int base = gid*4; base < E; base += ngroups*4){   // E % 4 == 0
    int4 r4 = *(const int4*)(src + base);
    int4 c4 = *(const int4*)(dst + base);
    unsigned a0 = *(const unsigned*)(lg8  + (size_t)r4.x*64 + q*4);
    unsigned a1 = *(const unsigned*)(lg8  + (size_t)r4.y*64 + q*4);
    unsigned a2 = *(const unsigned*)(lg8  + (size_t)r4.z*64 + q*4);
    unsigned a3 = *(const unsigned*)(lg8  + (size_t)r4.w*64 + q*4);
    unsigned b0 = *(const unsigned*)(lgp8 + (size_t)c4.x*64 + q*4);
    unsigned b1 = *(const unsigned*)(lgp8 + (size_t)c4.y*64 + q*4);
    unsigned b2 = *(const unsigned*)(lgp8 + (size_t)c4.z*64 + q*4);
    unsigned b3 = *(const unsigned*)(lgp8 + (size_t)c4.w*64 + q*4);
    float v0 = fp8_dot4(a0, b0);
    float v1 = fp8_dot4(a1, b1);
    float v2 = fp8_dot4(a2, b2);
    float v3 = fp8_dot4(a3, b3);
    #pragma unroll
    for (int o = 1; o < 16; o <<= 1){
      v0 += __shfl_xor(v0, o); v1 += __shfl_xor(v1, o);
      v2 += __shfl_xor(v2, o); v3 += __shfl_xor(v3, o);
    }
    if (q == 0){
      float4 vv = make_float4(v0*65536.f, v1*65536.f, v2*65536.f, v3*65536.f);
      *(float4*)(w + base) = vv;
      s  += vv.x + vv.y + vv.z + vv.w;
      ss += vv.x*vv.x + vv.y*vv.y + vv.z*vv.z + vv.w*vv.w;
    }
  }
  #pragma unroll
  for (int o = 1; o < 64; o <<= 1){ s += __shfl_xor(s, o); ss += __shfl_xor(ss, o); }
  __shared__ float ls[4], lss[4];
  if (lane == 0){ ls[wid] = s; lss[wid] = ss; }
  __syncthreads();
  if (t == 0){
    atomicAdd(&scal[0], ls[0]+ls[1]+ls[2]+ls[3]);
    atomicAdd(&scal[1], lss[0]+lss[1]+lss[2]+lss[3]);
  }
}

__global__ void finalize_k(float* scal, int E){
  double sum = (double)scal[0], sumsq = (double)scal[1];
  double mean = sum / (double)E;
  double var  = (sumsq - sum*sum/(double)E) / (double)(E-1);
  scal[2] = (float)mean;
  scal[3] = (float)sqrt(1e-4 / var);
}

// normalize bucket in place, deg = 1 + sum(w), dinv = rsqrt(deg) — fused, no atomics
__global__ __launch_bounds__(256) void degnorm_k(float* __restrict__ w, const int* __restrict__ off,
    const float* __restrict__ scal, float* __restrict__ dinv, int Nn){
  int n = blockIdx.x*256 + threadIdx.x;
  if (n < Nn){
    float mean = scal[2], k = scal[3];
    int s = off[n], e = off[n+1];
    float d = 1.0f;
    for (int j = s; j < e; j++){
      float v = (w[j] - mean) * k + 1.0f;
      w[j] = v;
      d += v;
    }
    dinv[n] = (d > 0.f) ? rsqrtf(d) : 0.f;
  }
}

// final edge weight, slot-parallel: w[e] *= dinv[dst[e]] * dinv[src[e]]
__global__ __launch_bounds__(256) void wfin_k(float* __restrict__ w, const int* __restrict__ src,
    const int* __restrict__ dst, const float* __restrict__ dinv, int E){
  int e = blockIdx.x*256 + threadIdx.x;
  if (e < E) w[e] = w[e] * dinv[dst[e]] * dinv[src[e]];
}

// CSR gather aggregation from bf16 h: wave per node, 2 channels/lane, bf16 out
__global__ __launch_bounds__(256) void agg_gather_k(const short* __restrict__ hb,
    const int* __restrict__ off, const int* __restrict__ src, const float* __restrict__ w,
    const float* __restrict__ dinv, short* __restrict__ aggb, int Nn){
  int n = blockIdx.x*4 + (threadIdx.x >> 6);
  int lane = threadIdx.x & 63;
  if (n >= Nn) return;
  float d = dinv[n];
  short2 hv = *(const short2*)(hb + (size_t)n*128 + lane*2);
  float acc0 = d*d*bf2f(hv.x), acc1 = d*d*bf2f(hv.y);
  int s = off[n], e = off[n+1];
  int j = s;
  for (; j + 1 < e; j += 2){
    int r0 = src[j], r1 = src[j+1];
    float w0 = w[j], w1 = w[j+1];
    short2 h0 = *(const short2*)(hb + (size_t)r0*128 + lane*2);
    short2 h1 = *(const short2*)(hb + (size_t)r1*128 + lane*2);
    acc0 += w0*bf2f(h0.x) + w1*bf2f(h1.x);
    acc1 += w0*bf2f(h0.y) + w1*bf2f(h1.y);
  }
  if (j < e){
    short2 h0 = *(const short2*)(hb + (size_t)src[j]*128 + lane*2);
    float w0 = w[j];
    acc0 += w0*bf2f(h0.x); acc1 += w0*bf2f(h0.y);
  }
  short2 o; o.x = f2bf(acc0); o.y = f2bf(acc1);
  *(short2*)(aggb + (size_t)n*128 + lane*2) = o;
}

extern "C" void kernel_launch(void* const* d_in, const int* in_sizes, int n_in,
                              void* d_out, int out_size, void* d_ws, size_t ws_size,
                              hipStream_t stream){
  const float* x      = (const float*)d_in[0];
  const int*   ei     = (const int*)  d_in[1];
  const float* w1     = (const float*)d_in[2];
  const float* b1     = (const float*)d_in[3];
  const float* w2     = (const float*)d_in[4];
  const float* b2     = (const float*)d_in[5];
  const float* w3     = (const float*)d_in[6];
  const float* b3     = (const float*)d_in[7];
  const float* pars   = (const float*)d_in[8];
  const float* lin0w  = (const float*)d_in[9];
  const float* lin0b  = (const float*)d_in[10];
  const float* lin1w  = (const float*)d_in[11];
  const float* lin1b  = (const float*)d_in[12];
  const float* cw1    = (const float*)d_in[13];
  float* out          = (float*)d_out;

  float* ws = (float*)d_ws;
  // workspace layout (float-element offsets)
  int*   cnt     = (int*)(ws + 0);            //    50,000
  int*   off     = (int*)(ws + 50048);        //    50,001
  int*   cursor  = (int*)(ws + 100096);       //    50,000
  int*   csr_src = (int*)(ws + 150144);       //   800,000
  float* csr_w   = ws + 950144;               //   800,000 (raw ew -> normalized -> final)
  int*   bsum    = (int*)(ws + 1750400);      //        64
  short* lin0wt  = (short*)(ws + 1751000);    //  16,384 shorts
  short* cw1t0   = lin0wt + 16384;            //  16,384
  short* cw1t1   = cw1t0 + 16384;             //  16,384
  short* lin1wt  = cw1t1 + 16384;             //   8,192
  unsigned char* lg8  = (unsigned char*)(ws + 1800000);  // 3.2M bytes (fp8 logits)
  unsigned char* lgp8 = (unsigned char*)(ws + 2600000);  // 3.2M bytes (fp8 logitsP)
  float* dinv    = ws + 5800000;              //    50,000
  float* scal    = ws + 5850048;              //        16
  short* bufAb   = (short*)(ws + 5900000);    // 6.4M shorts (x0)
  short* bufCb   = (short*)(ws + 9100000);    // 6.4M shorts (h after layer0)
  short* aggb    = (short*)(ws + 12300000);   // 6.4M shorts (aggregation out)
  short* bufBb   = (short*)(ws + 15500000);   // 6.4M shorts (h after layer1)
  short* w1t     = (short*)(ws + 18700000);   // 106,496 shorts MLP weights
  short* w2t     = w1t + 65536;
  short* w3t     = w2t + 32768;
  short* Pt      = w3t + 4096;
  short* xb      = (short*)(ws + 18800000);   // 6.4M shorts (bf16 x)
  int*   csr_dst = (int*)(ws + 22000000);     //   800,000 (ends 22,800,000 ~ 91 MB)

  const int Mn = NN, E = NE;
  const int* erow = ei;
  const int* ecol = ei + E;
  const float beta0 = 0.69314718055994530942f;  // ln(2)
  const float beta1 = 0.40546510810816438198f;  // ln(1.5)
  const int nScanB = (Mn + 1023) / 1024;        // 49 <= 64
  const int nGB = (Mn + 31) / 32;               // bgemm grid

  // 1) init + weight prep
  zero_cnt_k<<<(Mn+255)/256, 256, 0, stream>>>(cnt, scal, Mn);
  prep_k<<<(163840+255)/256, 256, 0, stream>>>(w1, w2, w3, pars, lin0w, cw1, lin1w,
                                               w1t, w2t, w3t, Pt, lin0wt, cw1t0, cw1t1, lin1wt);
  // 2) CSR structure (independent of ew): count + scan + scatter (src,dst)
  count_k<<<(E+255)/256, 256, 0, stream>>>(ecol, cnt, E);
  scan_sums_k<<<nScanB, 256, 0, stream>>>(cnt, bsum, Mn);
  scan_bsum_k<<<1, 64, 0, stream>>>(bsum, nScanB);
  scan_final_k<<<nScanB, 256, 0, stream>>>(cnt, bsum, off, cursor, Mn, E);
  scatter_k<<<(E+255)/256, 256, 0, stream>>>(erow, ecol, cursor, csr_src, csr_dst, E);
  // 3) fused bf16-MFMA MLP chain (16 rows/block) -> lg8, lgp8 (fp8) + xb dump
  mlp_mfma_k<<<(Mn+15)/16, 256, 0, stream>>>(x, w1t, b1, w2t, b2, w3t, b3, Pt,
                                             lg8, lgp8, xb, Mn);
  // 4) ew: 4-edge-batched groups over CSR slots + stats; degnorm+dinv; final weights
  ew2_k<<<1024, 256, 0, stream>>>(lg8, lgp8, csr_src, csr_dst, csr_w, scal, E);
  finalize_k<<<1, 1, 0, stream>>>(scal, E);
  degnorm_k<<<(Mn+255)/256, 256, 0, stream>>>(csr_w, off, scal, dinv, Mn);
  wfin_k<<<(E+255)/256, 256, 0, stream>>>(csr_w, csr_src, csr_dst, dinv, E);
  // 5) x0 = relu(xb@lin0wt + lin0b) -> bufAb (bf16, MFMA)
  bgemm_k<2,true,false,true><<<nGB, 256, 0, stream>>>(xb, lin0wt, lin0b, nullptr, nullptr, bufAb, Mn, 0.f);
  // 6) layer 0: gather agg (bf16) from bufAb; hnext -> bufCb (bf16, MFMA resid)
  agg_gather_k<<<(Mn+3)/4, 256, 0, stream>>>(bufAb, off, csr_src, csr_w, dinv, aggb, Mn);
  bgemm_k<2,true,true,true><<<nGB, 256, 0, stream>>>(aggb, cw1t0, nullptr, aggb, nullptr, bufCb, Mn, beta0);
  // 7) layer 1: gather agg from bufCb; hnext -> bufBb (bf16, MFMA resid)
  agg_gather_k<<<(Mn+3)/4, 256, 0, stream>>>(bufCb, off, csr_src, csr_w, dinv, aggb, Mn);
  bgemm_k<2,true,true,true><<<nGB, 256, 0, stream>>>(aggb, cw1t1, nullptr, aggb, nullptr, bufBb, Mn, beta1);
  // 8) out = bufBb @ lin1wt + lin1b (fp32 out, MFMA)
  bgemm_k<1,false,false,false><<<nGB, 256, 0, stream>>>(bufBb, lin1wt, lin1b, nullptr, out, nullptr, Mn, 0.f);
}

// Round 13
// 430.936 us; speedup vs baseline: 1.1275x; 1.1275x over previous
//
#include <hip/hip_runtime.h>
#include <hip/hip_bf16.h>
#include <hip/hip_fp16.h>
#include <math.h>

#define NN 50000
#define NE 800000

typedef __attribute__((ext_vector_type(8))) short bf16x8;
typedef __attribute__((ext_vector_type(4))) float f32x4;

__device__ __forceinline__ short f2bf(float f){
  unsigned u = __float_as_uint(f);
  unsigned r = (u + 0x7fffu + ((u >> 16) & 1u)) >> 16;
  return (short)r;
}
__device__ __forceinline__ float bf2f(short s){
  return __uint_as_float(((unsigned)(unsigned short)s) << 16);
}

// ---- fp8 e4m3 via exact f16 scaling ----
__device__ __forceinline__ unsigned f2fp8(float f){
  __half h = __float2half(f * 0.00390625f);          // v * 2^-8, RNE
  unsigned hb = (unsigned)__half_as_ushort(h);
  unsigned s = hb >> 15;
  unsigned mag = hb & 0x7fffu;
  mag = mag + 0x3fu + ((mag >> 7) & 1u);             // RNE drop of low 7 bits
  unsigned m8 = mag >> 7;
  if (m8 > 0x7eu) m8 = 0x7eu;
  return (s << 7) | m8;
}
__device__ __forceinline__ void fp8x4_dec(unsigned u, float2& lo, float2& hi){
  unsigned l = ((u & 0x80u) << 8) | ((u & 0x7fu) << 7)
             | ((u & 0x8000u) << 16) | ((u & 0x7f00u) << 15);
  unsigned h = ((u & 0x800000u) >> 8) | ((u & 0x7f0000u) >> 9)
             | (u & 0x80000000u) | ((u & 0x7f000000u) >> 1);
  __half2 hl = *(__half2*)&l;
  __half2 hh = *(__half2*)&h;
  lo = __half22float2(hl);
  hi = __half22float2(hh);
}
__device__ __forceinline__ float fp8_dot4(unsigned a, unsigned b){
  float2 al, ah, bl, bh;
  fp8x4_dec(a, al, ah); fp8x4_dec(b, bl, bh);
  return al.x*bl.x + al.y*bl.y + ah.x*bh.x + ah.y*bh.y;
}

// ---------------- zero cnt + stat scalars ----------------
__global__ __launch_bounds__(256) void zero_cnt_k(int* __restrict__ cnt, float* __restrict__ scal, int n){
  int i = blockIdx.x*256 + threadIdx.x;
  if (i < n) cnt[i] = 0;
  if (blockIdx.x == 0 && threadIdx.x < 16) scal[threadIdx.x] = 0.0f;
}

// ---------------- weight prep: transpose + bf16 convert (MLP + GCN weights) ----------------
__global__ __launch_bounds__(256) void prep_k(const float* __restrict__ w1,
    const float* __restrict__ w2, const float* __restrict__ w3, const float* __restrict__ pars,
    const float* __restrict__ lin0w, const float* __restrict__ cw1, const float* __restrict__ lin1w,
    short* __restrict__ w1t, short* __restrict__ w2t, short* __restrict__ w3t, short* __restrict__ Pt,
    short* __restrict__ lin0wt, short* __restrict__ cw1t0, short* __restrict__ cw1t1,
    short* __restrict__ lin1wt){
  int idx = blockIdx.x*256 + threadIdx.x;
  if (idx < 65536){
    int n = idx >> 7, k = idx & 127;
    w1t[idx] = f2bf(w1[k*512 + n]);
  } else if (idx < 98304){
    int i = idx - 65536; int n = i >> 9, k = i & 511;
    w2t[i] = f2bf(w2[k*64 + n]);
  } else if (idx < 102400){
    int i = idx - 98304; int n = i >> 6, k = i & 63;
    w3t[i] = f2bf(w3[k*64 + n]);
  } else if (idx < 106496){
    int i = idx - 102400; int n = i >> 6, k = i & 63;
    Pt[i] = f2bf(fmaxf(2.f*pars[k*64 + n], 0.f));
  } else if (idx < 122880){
    int i = idx - 106496; int n = i >> 7, k = i & 127;
    lin0wt[i] = f2bf(lin0w[k*128 + n]);
  } else if (idx < 139264){
    int i = idx - 122880; int n = i >> 7, k = i & 127;
    cw1t0[i] = f2bf(cw1[k*128 + n]);
  } else if (idx < 155648){
    int i = idx - 139264; int n = i >> 7, k = i & 127;
    cw1t1[i] = f2bf(cw1[16384 + k*128 + n]);
  } else if (idx < 163840){
    int i = idx - 155648; int n = i >> 7, k = i & 127;   // n in [0,64)
    lin1wt[i] = f2bf(lin1w[k*64 + n]);
  }
}

// ---------------- fused bf16-MFMA MLP chain (32 rows/block, r11 version) ----------------
__global__ __launch_bounds__(256) void mlp_mfma_k(
    const float* __restrict__ x,
    const short* __restrict__ w1t, const float* __restrict__ b1,
    const short* __restrict__ w2t, const float* __restrict__ b2,
    const short* __restrict__ w3t, const float* __restrict__ b3,
    const short* __restrict__ Pt,
    unsigned char* __restrict__ lg8, unsigned char* __restrict__ lgp8,
    short* __restrict__ xb, int M)
{
  __shared__ short xs [32][136];
  __shared__ short h1s[32][520];
  __shared__ short h2s[32][72];   // phase2 out; reused as logitsP staging in phase 4
  __shared__ short lgs[32][72];
  const int t = threadIdx.x;
  const int wave = t >> 6, lane = t & 63;
  const int quad = lane >> 4, l16 = lane & 15;
  const int m0 = blockIdx.x * 32;

  for (int task = t; task < 512; task += 256){
    int row = task >> 4, c0 = (task & 15) * 8;
    float4 v0 = make_float4(0,0,0,0), v1 = v0;
    if (m0 + row < M){
      v0 = *(const float4*)(x + (size_t)(m0+row)*128 + c0);
      v1 = *(const float4*)(x + (size_t)(m0+row)*128 + c0 + 4);
    }
    bf16x8 s;
    s[0]=f2bf(v0.x); s[1]=f2bf(v0.y); s[2]=f2bf(v0.z); s[3]=f2bf(v0.w);
    s[4]=f2bf(v1.x); s[5]=f2bf(v1.y); s[6]=f2bf(v1.z); s[7]=f2bf(v1.w);
    *(bf16x8*)&xs[row][c0] = s;
  }
  __syncthreads();

  // ---- Phase 1: h1 = relu(x @ w1 + b1) ----
  {
    f32x4 acc[2][8];
    #pragma unroll
    for (int mt=0;mt<2;mt++)
      #pragma unroll
      for (int nt=0;nt<8;nt++) acc[mt][nt] = (f32x4){0.f,0.f,0.f,0.f};
    for (int k0 = 0; k0 < 128; k0 += 32){
      bf16x8 a0 = *(const bf16x8*)&xs[l16     ][k0 + quad*8];
      bf16x8 a1 = *(const bf16x8*)&xs[16 + l16][k0 + quad*8];
      #pragma unroll
      for (int nt = 0; nt < 8; nt++){
        int n = wave*128 + nt*16 + l16;
        bf16x8 b = *(const bf16x8*)(w1t + (size_t)n*128 + k0 + quad*8);
        acc[0][nt] = __builtin_amdgcn_mfma_f32_16x16x32_bf16(a0, b, acc[0][nt], 0,0,0);
        acc[1][nt] = __builtin_amdgcn_mfma_f32_16x16x32_bf16(a1, b, acc[1][nt], 0,0,0);
      }
    }
    #pragma unroll
    for (int nt = 0; nt < 8; nt++){
      int n = wave*128 + nt*16 + l16;
      float bb = b1[n];
      #pragma unroll
      for (int mt = 0; mt < 2; mt++){
        #pragma unroll
        for (int r = 0; r < 4; r++){
          int row = mt*16 + quad*4 + r;
          h1s[row][n] = f2bf(fmaxf(acc[mt][nt][r] + bb, 0.f));
        }
      }
    }
  }
  __syncthreads();

  // ---- Phase 2: h2 = relu(h1 @ w2 + b2) ----
  {
    f32x4 acc[2];
    acc[0] = (f32x4){0.f,0.f,0.f,0.f}; acc[1] = acc[0];
    const int n = wave*16 + l16;
    for (int k0 = 0; k0 < 512; k0 += 32){
      bf16x8 b  = *(const bf16x8*)(w2t + (size_t)n*512 + k0 + quad*8);
      bf16x8 a0 = *(const bf16x8*)&h1s[l16     ][k0 + quad*8];
      bf16x8 a1 = *(const bf16x8*)&h1s[16 + l16][k0 + quad*8];
      acc[0] = __builtin_amdgcn_mfma_f32_16x16x32_bf16(a0, b, acc[0], 0,0,0);
      acc[1] = __builtin_amdgcn_mfma_f32_16x16x32_bf16(a1, b, acc[1], 0,0,0);
    }
    float bb = b2[n];
    #pragma unroll
    for (int mt = 0; mt < 2; mt++)
      #pragma unroll
      for (int r = 0; r < 4; r++)
        h2s[mt*16 + quad*4 + r][n] = f2bf(fmaxf(acc[mt][r] + bb, 0.f));
  }
  __syncthreads();

  // ---- Phase 3: logits = h2 @ w3 + b3 -> lgs ----
  {
    f32x4 acc[2];
    acc[0] = (f32x4){0.f,0.f,0.f,0.f}; acc[1] = acc[0];
    const int n = wave*16 + l16;
    for (int k0 = 0; k0 < 64; k0 += 32){
      bf16x8 b  = *(const bf16x8*)(w3t + (size_t)n*64 + k0 + quad*8);
      bf16x8 a0 = *(const bf16x8*)&h2s[l16     ][k0 + quad*8];
      bf16x8 a1 = *(const bf16x8*)&h2s[16 + l16][k0 + quad*8];
      acc[0] = __builtin_amdgcn_mfma_f32_16x16x32_bf16(a0, b, acc[0], 0,0,0);
      acc[1] = __builtin_amdgcn_mfma_f32_16x16x32_bf16(a1, b, acc[1], 0,0,0);
    }
    float bb = b3[n];
    #pragma unroll
    for (int mt = 0; mt < 2; mt++)
      #pragma unroll
      for (int r = 0; r < 4; r++)
        lgs[mt*16 + quad*4 + r][n] = f2bf(acc[mt][r] + bb);
  }
  __syncthreads();

  // ---- Phase 4: logitsP = logits @ relu(2P) -> h2s ----
  {
    f32x4 acc[2];
    acc[0] = (f32x4){0.f,0.f,0.f,0.f}; acc[1] = acc[0];
    const int n = wave*16 + l16;
    for (int k0 = 0; k0 < 64; k0 += 32){
      bf16x8 b  = *(const bf16x8*)(Pt + (size_t)n*64 + k0 + quad*8);
      bf16x8 a0 = *(const bf16x8*)&lgs[l16     ][k0 + quad*8];
      bf16x8 a1 = *(const bf16x8*)&lgs[16 + l16][k0 + quad*8];
      acc[0] = __builtin_amdgcn_mfma_f32_16x16x32_bf16(a0, b, acc[0], 0,0,0);
      acc[1] = __builtin_amdgcn_mfma_f32_16x16x32_bf16(a1, b, acc[1], 0,0,0);
    }
    #pragma unroll
    for (int mt = 0; mt < 2; mt++)
      #pragma unroll
      for (int r = 0; r < 4; r++)
        h2s[mt*16 + quad*4 + r][n] = f2bf(acc[mt][r]);
  }
  __syncthreads();

  // ---- cooperative store: lgs -> lg8 (fp8), h2s -> lgp8 (fp8) ----
  {
    int row = t >> 3, c0 = (t & 7) * 8;
    int gm = m0 + row;
    if (gm < M){
      const short* pl = &lgs[row][c0];
      const short* pp = &h2s[row][c0];
      unsigned a0 = 0, a1 = 0, b0 = 0, b1 = 0;
      #pragma unroll
      for (int j = 0; j < 4; j++){
        a0 |= f2fp8(bf2f(pl[j]))     << (8*j);
        a1 |= f2fp8(bf2f(pl[4+j]))   << (8*j);
        b0 |= f2fp8(bf2f(pp[j]))     << (8*j);
        b1 |= f2fp8(bf2f(pp[4+j]))   << (8*j);
      }
      uint2 av; av.x = a0; av.y = a1;
      uint2 bv; bv.x = b0; bv.y = b1;
      *(uint2*)(lg8  + (size_t)gm*64 + c0) = av;
      *(uint2*)(lgp8 + (size_t)gm*64 + c0) = bv;
    }
  }
  // dump staged bf16 x -> xb (feeds x0 GEMM)
  for (int task = t; task < 512; task += 256){
    int row = task >> 4, c0 = (task & 15) * 8;
    int gm = m0 + row;
    if (gm < M)
      *(bf16x8*)(xb + (size_t)gm*128 + c0) = *(const bf16x8*)&xs[row][c0];
  }
}

// ---------------- bf16 MFMA GEMM: C[M][N] = EPI(A[M][128] @ Bt[N][128]^T) ----------------
template<int NT, bool RELU, bool RESID, bool BF16OUT>
__global__ __launch_bounds__(256) void bgemm_k(
    const short* __restrict__ A, const short* __restrict__ Bt,
    const float* __restrict__ bias, const short* __restrict__ extra,
    float* __restrict__ C, short* __restrict__ Cb, int M, float beta)
{
  const int N = NT*64;
  __shared__ short As[32][136];
  const int t = threadIdx.x;
  const int wave = t >> 6, lane = t & 63;
  const int quad = lane >> 4, l16 = lane & 15;
  const int m0 = blockIdx.x * 32;

  for (int task = t; task < 512; task += 256){
    int row = task >> 4, c0 = (task & 15) * 8;
    bf16x8 v = {0,0,0,0,0,0,0,0};
    if (m0 + row < M) v = *(const bf16x8*)(A + (size_t)(m0+row)*128 + c0);
    *(bf16x8*)&As[row][c0] = v;
  }
  __syncthreads();

  f32x4 acc[2][NT];
  #pragma unroll
  for (int mt=0;mt<2;mt++)
    #pragma unroll
    for (int nt=0;nt<NT;nt++) acc[mt][nt] = (f32x4){0.f,0.f,0.f,0.f};

  #pragma unroll
  for (int k0 = 0; k0 < 128; k0 += 32){
    bf16x8 a0 = *(const bf16x8*)&As[l16     ][k0 + quad*8];
    bf16x8 a1 = *(const bf16x8*)&As[16 + l16][k0 + quad*8];
    #pragma unroll
    for (int nt = 0; nt < NT; nt++){
      int n = (wave*NT + nt)*16 + l16;
      bf16x8 b = *(const bf16x8*)(Bt + (size_t)n*128 + k0 + quad*8);
      acc[0][nt] = __builtin_amdgcn_mfma_f32_16x16x32_bf16(a0, b, acc[0][nt], 0,0,0);
      acc[1][nt] = __builtin_amdgcn_mfma_f32_16x16x32_bf16(a1, b, acc[1][nt], 0,0,0);
    }
  }

  #pragma unroll
  for (int nt = 0; nt < NT; nt++){
    int n = (wave*NT + nt)*16 + l16;
    float bb = (bias != nullptr) ? bias[n] : 0.f;
    #pragma unroll
    for (int mt = 0; mt < 2; mt++){
      #pragma unroll
      for (int r = 0; r < 4; r++){
        int gm = m0 + mt*16 + quad*4 + r;
        if (gm >= M) continue;
        float v = acc[mt][nt][r];
        if (RESID){
          float ex = bf2f(extra[(size_t)gm*N + n]);
          v = beta*v + (1.f - beta)*ex;
        }
        v += bb;
        if (RELU) v = fmaxf(v, 0.f);
        if (BF16OUT) Cb[(size_t)gm*N + n] = f2bf(v);
        else         C [(size_t)gm*N + n] = v;
      }
    }
  }
}

// ---------------- count in-degree (int) at col ----------------
__global__ __launch_bounds__(256) void count_k(const int* __restrict__ col, int* __restrict__ cnt, int E){
  int e = blockIdx.x*256 + threadIdx.x;
  if (e < E) atomicAdd(&cnt[col[e]], 1);
}

// ---------------- multi-block exclusive scan (3 phases) ----------------
__global__ __launch_bounds__(256) void scan_sums_k(const int* __restrict__ cnt, int* __restrict__ bsum, int n){
  __shared__ int s[256];
  const int t = threadIdx.x;
  int i = blockIdx.x*1024 + t*4;
  int4 v = make_int4(0,0,0,0);
  if (i + 3 < n) v = *(const int4*)(cnt + i);
  else {
    if (i   < n) v.x = cnt[i];
    if (i+1 < n) v.y = cnt[i+1];
    if (i+2 < n) v.z = cnt[i+2];
    if (i+3 < n) v.w = cnt[i+3];
  }
  s[t] = v.x + v.y + v.z + v.w;
  __syncthreads();
  for (int st = 128; st; st >>= 1){
    if (t < st) s[t] += s[t + st];
    __syncthreads();
  }
  if (t == 0) bsum[blockIdx.x] = s[0];
}

__global__ __launch_bounds__(64) void scan_bsum_k(int* __restrict__ bsum, int nb){
  int t = threadIdx.x;
  int own = (t < nb) ? bsum[t] : 0;
  int v = own;
  #pragma unroll
  for (int off = 1; off < 64; off <<= 1){
    int o = __shfl_up(v, off, 64);
    if (t >= off) v += o;
  }
  if (t < nb) bsum[t] = v - own;   // exclusive
}

__global__ __launch_bounds__(256) void scan_final_k(const int* __restrict__ cnt, const int* __restrict__ bsum,
    int* __restrict__ off, int* __restrict__ cursor, int n, int total){
  __shared__ int s[256];
  const int t = threadIdx.x;
  int i = blockIdx.x*1024 + t*4;
  int4 v = make_int4(0,0,0,0);
  if (i + 3 < n) v = *(const int4*)(cnt + i);
  else {
    if (i   < n) v.x = cnt[i];
    if (i+1 < n) v.y = cnt[i+1];
    if (i+2 < n) v.z = cnt[i+2];
    if (i+3 < n) v.w = cnt[i+3];
  }
  int tsum = v.x + v.y + v.z + v.w;
  s[t] = tsum;
  __syncthreads();
  #pragma unroll
  for (int st = 1; st < 256; st <<= 1){
    int a = (t >= st) ? s[t - st] : 0;
    __syncthreads();
    s[t] += a;
    __syncthreads();
  }
  int base = s[t] - tsum + bsum[blockIdx.x];
  int o0 = base, o1 = o0 + v.x, o2 = o1 + v.y, o3 = o2 + v.z;
  if (i   < n){ off[i]   = o0; cursor[i]   = o0; }
  if (i+1 < n){ off[i+1] = o1; cursor[i+1] = o1; }
  if (i+2 < n){ off[i+2] = o2; cursor[i+2] = o2; }
  if (i+3 < n){ off[i+3] = o3; cursor[i+3] = o3; }
  if (blockIdx.x == 0 && t == 0) off[n] = total;
}

// bucket edges by destination; store src AND dst per slot
__global__ __launch_bounds__(256) void scatter_k(const int* __restrict__ row, const int* __restrict__ col,
    int* __restrict__ cursor, int* __restrict__ csr_src, int* __restrict__ csr_dst, int E){
  int e = blockIdx.x*256 + threadIdx.x;
  if (e < E){
    int r = row[e], c = col[e];
    int slot = atomicAdd(&cursor[c], 1);
    csr_src[slot] = r;
    csr_dst[slot] = c;
  }
}

// ---------------- ew over CSR slots: 16-lane groups, explicit 4-edge batch pipeline ----------------
__global__ __launch_bounds__(256) void ew2_k(const unsigned char* __restrict__ lg8,
    const unsigned char* __restrict__ lgp8,
    const int* __restrict__ src, const int* __restrict__ dst,
    float* __restrict__ w, float* __restrict__ scal, int E){
  const int t = threadIdx.x;
  const int lane = t & 63, wid = t >> 6;
  const int g = lane >> 4, q = lane & 15;
  const int gid = (blockIdx.x*4 + wid)*4 + g;     // global 16-lane group id
  const int ngroups = gridDim.x*16;
  float s = 0.f, ss = 0.f;
  for (int base = gid*4; base < E; base += ngroups*4){   // E % 4 == 0
    int4 r4 = *(const int4*)(src + base);
    int4 c4 = *(const int4*)(dst + base);
    unsigned a0 = *(const unsigned*)(lg8  + (size_t)r4.x*64 + q*4);
    unsigned a1 = *(const unsigned*)(lg8  + (size_t)r4.y*64 + q*4);
    unsigned a2 = *(const unsigned*)(lg8  + (size_t)r4.z*64 + q*4);
    unsigned a3 = *(const unsigned*)(lg8  + (size_t)r4.w*64 + q*4);
    unsigned b0 = *(const unsigned*)(lgp8 + (size_t)c4.x*64 + q*4);
    unsigned b1 = *(const unsigned*)(lgp8 + (size_t)c4.y*64 + q*4);
    unsigned b2 = *(const unsigned*)(lgp8 + (size_t)c4.z*64 + q*4);
    unsigned b3 = *(const unsigned*)(lgp8 + (size_t)c4.w*64 + q*4);
    float v0 = fp8_dot4(a0, b0);
    float v1 = fp8_dot4(a1, b1);
    float v2 = fp8_dot4(a2, b2);
    float v3 = fp8_dot4(a3, b3);
    #pragma unroll
    for (int o = 1; o < 16; o <<= 1){
      v0 += __shfl_xor(v0, o); v1 += __shfl_xor(v1, o);
      v2 += __shfl_xor(v2, o); v3 += __shfl_xor(v3, o);
    }
    if (q == 0){
      float4 vv = make_float4(v0*65536.f, v1*65536.f, v2*65536.f, v3*65536.f);
      *(float4*)(w + base) = vv;
      s  += vv.x + vv.y + vv.z + vv.w;
      ss += vv.x*vv.x + vv.y*vv.y + vv.z*vv.z + vv.w*vv.w;
    }
  }
  #pragma unroll
  for (int o = 1; o < 64; o <<= 1){ s += __shfl_xor(s, o); ss += __shfl_xor(ss, o); }
  __shared__ float ls[4], lss[4];
  if (lane == 0){ ls[wid] = s; lss[wid] = ss; }
  __syncthreads();
  if (t == 0){
    atomicAdd(&scal[0], ls[0]+ls[1]+ls[2]+ls[3]);
    atomicAdd(&scal[1], lss[0]+lss[1]+lss[2]+lss[3]);
  }
}

__global__ void finalize_k(float* scal, int E){
  double sum = (double)scal[0], sumsq = (double)scal[1];
  double mean = sum / (double)E;
  double var  = (sumsq - sum*sum/(double)E) / (double)(E-1);
  scal[2] = (float)mean;
  scal[3] = (float)sqrt(1e-4 / var);
}

// normalize bucket in place, deg = 1 + sum(w), dinv = rsqrt(deg) — fused, no atomics
__global__ __launch_bounds__(256) void degnorm_k(float* __restrict__ w, const int* __restrict__ off,
    const float* __restrict__ scal, float* __restrict__ dinv, int Nn){
  int n = blockIdx.x*256 + threadIdx.x;
  if (n < Nn){
    float mean = scal[2], k = scal[3];
    int s = off[n], e = off[n+1];
    float d = 1.0f;
    for (int j = s; j < e; j++){
      float v = (w[j] - mean) * k + 1.0f;
      w[j] = v;
      d += v;
    }
    dinv[n] = (d > 0.f) ? rsqrtf(d) : 0.f;
  }
}

// final edge weight, slot-parallel: w[e] *= dinv[dst[e]] * dinv[src[e]]
__global__ __launch_bounds__(256) void wfin_k(float* __restrict__ w, const int* __restrict__ src,
    const int* __restrict__ dst, const float* __restrict__ dinv, int E){
  int e = blockIdx.x*256 + threadIdx.x;
  if (e < E) w[e] = w[e] * dinv[dst[e]] * dinv[src[e]];
}

// CSR gather aggregation from bf16 h: wave per node, 8-wide batched independent gathers
__global__ __launch_bounds__(256) void agg_gather_k(const short* __restrict__ hb,
    const int* __restrict__ off, const int* __restrict__ src, const float* __restrict__ w,
    const float* __restrict__ dinv, short* __restrict__ aggb, int Nn){
  int n = blockIdx.x*4 + (threadIdx.x >> 6);
  int lane = threadIdx.x & 63;
  if (n >= Nn) return;
  float d = dinv[n];
  short2 hv = *(const short2*)(hb + (size_t)n*128 + lane*2);
  float acc0 = d*d*bf2f(hv.x), acc1 = d*d*bf2f(hv.y);
  int s = off[n], e = off[n+1];
  int j = s;
  // 8-edge batches: load all indices+weights first, issue 8 independent row-gathers,
  // then accumulate — keeps 8 cache-line fetches in flight per wave.
  for (; j + 7 < e; j += 8){
    int4 i0 = *(const int4*)(src + j);
    int4 i1 = *(const int4*)(src + j + 4);
    float4 w0 = *(const float4*)(w + j);
    float4 w1 = *(const float4*)(w + j + 4);
    short2 h0 = *(const short2*)(hb + (size_t)i0.x*128 + lane*2);
    short2 h1 = *(const short2*)(hb + (size_t)i0.y*128 + lane*2);
    short2 h2 = *(const short2*)(hb + (size_t)i0.z*128 + lane*2);
    short2 h3 = *(const short2*)(hb + (size_t)i0.w*128 + lane*2);
    short2 h4 = *(const short2*)(hb + (size_t)i1.x*128 + lane*2);
    short2 h5 = *(const short2*)(hb + (size_t)i1.y*128 + lane*2);
    short2 h6 = *(const short2*)(hb + (size_t)i1.z*128 + lane*2);
    short2 h7 = *(const short2*)(hb + (size_t)i1.w*128 + lane*2);
    acc0 += w0.x*bf2f(h0.x) + w0.y*bf2f(h1.x) + w0.z*bf2f(h2.x) + w0.w*bf2f(h3.x)
          + w1.x*bf2f(h4.x) + w1.y*bf2f(h5.x) + w1.z*bf2f(h6.x) + w1.w*bf2f(h7.x);
    acc1 += w0.x*bf2f(h0.y) + w0.y*bf2f(h1.y) + w0.z*bf2f(h2.y) + w0.w*bf2f(h3.y)
          + w1.x*bf2f(h4.y) + w1.y*bf2f(h5.y) + w1.z*bf2f(h6.y) + w1.w*bf2f(h7.y);
  }
  for (; j < e; j++){
    short2 h0 = *(const short2*)(hb + (size_t)src[j]*128 + lane*2);
    float w0 = w[j];
    acc0 += w0*bf2f(h0.x); acc1 += w0*bf2f(h0.y);
  }
  short2 o; o.x = f2bf(acc0); o.y = f2bf(acc1);
  *(short2*)(aggb + (size_t)n*128 + lane*2) = o;
}

extern "C" void kernel_launch(void* const* d_in, const int* in_sizes, int n_in,
                              void* d_out, int out_size, void* d_ws, size_t ws_size,
                              hipStream_t stream){
  const float* x      = (const float*)d_in[0];
  const int*   ei     = (const int*)  d_in[1];
  const float* w1     = (const float*)d_in[2];
  const float* b1     = (const float*)d_in[3];
  const float* w2     = (const float*)d_in[4];
  const float* b2     = (const float*)d_in[5];
  const float* w3     = (const float*)d_in[6];
  const float* b3     = (const float*)d_in[7];
  const float* pars   = (const float*)d_in[8];
  const float* lin0w  = (const float*)d_in[9];
  const float* lin0b  = (const float*)d_in[10];
  const float* lin1w  = (const float*)d_in[11];
  const float* lin1b  = (const float*)d_in[12];
  const float* cw1    = (const float*)d_in[13];
  float* out          = (float*)d_out;

  float* ws = (float*)d_ws;
  // workspace layout (float-element offsets)
  int*   cnt     = (int*)(ws + 0);            //    50,000
  int*   off     = (int*)(ws + 50048);        //    50,001
  int*   cursor  = (int*)(ws + 100096);       //    50,000
  int*   csr_src = (int*)(ws + 150144);       //   800,000
  float* csr_w   = ws + 950144;               //   800,000 (raw ew -> normalized -> final)
  int*   bsum    = (int*)(ws + 1750400);      //        64
  short* lin0wt  = (short*)(ws + 1751000);    //  16,384 shorts
  short* cw1t0   = lin0wt + 16384;            //  16,384
  short* cw1t1   = cw1t0 + 16384;             //  16,384
  short* lin1wt  = cw1t1 + 16384;             //   8,192
  unsigned char* lg8  = (unsigned char*)(ws + 1800000);  // 3.2M bytes (fp8 logits)
  unsigned char* lgp8 = (unsigned char*)(ws + 2600000);  // 3.2M bytes (fp8 logitsP)
  float* dinv    = ws + 5800000;              //    50,000
  float* scal    = ws + 5850048;              //        16
  short* bufAb   = (short*)(ws + 5900000);    // 6.4M shorts (x0)
  short* bufCb   = (short*)(ws + 9100000);    // 6.4M shorts (h after layer0)
  short* aggb    = (short*)(ws + 12300000);   // 6.4M shorts (aggregation out)
  short* bufBb   = (short*)(ws + 15500000);   // 6.4M shorts (h after layer1)
  short* w1t     = (short*)(ws + 18700000);   // 106,496 shorts MLP weights
  short* w2t     = w1t + 65536;
  short* w3t     = w2t + 32768;
  short* Pt      = w3t + 4096;
  short* xb      = (short*)(ws + 18800000);   // 6.4M shorts (bf16 x)
  int*   csr_dst = (int*)(ws + 22000000);     //   800,000 (ends 22,800,000 ~ 91 MB)

  const int Mn = NN, E = NE;
  const int* erow = ei;
  const int* ecol = ei + E;
  const float beta0 = 0.69314718055994530942f;  // ln(2)
  const float beta1 = 0.40546510810816438198f;  // ln(1.5)
  const int nScanB = (Mn + 1023) / 1024;        // 49 <= 64
  const int nGB = (Mn + 31) / 32;               // bgemm grid

  // 1) init + weight prep
  zero_cnt_k<<<(Mn+255)/256, 256, 0, stream>>>(cnt, scal, Mn);
  prep_k<<<(163840+255)/256, 256, 0, stream>>>(w1, w2, w3, pars, lin0w, cw1, lin1w,
                                               w1t, w2t, w3t, Pt, lin0wt, cw1t0, cw1t1, lin1wt);
  // 2) CSR structure (independent of ew): count + scan + scatter (src,dst)
  count_k<<<(E+255)/256, 256, 0, stream>>>(ecol, cnt, E);
  scan_sums_k<<<nScanB, 256, 0, stream>>>(cnt, bsum, Mn);
  scan_bsum_k<<<1, 64, 0, stream>>>(bsum, nScanB);
  scan_final_k<<<nScanB, 256, 0, stream>>>(cnt, bsum, off, cursor, Mn, E);
  scatter_k<<<(E+255)/256, 256, 0, stream>>>(erow, ecol, cursor, csr_src, csr_dst, E);
  // 3) fused bf16-MFMA MLP chain (32 rows/block) -> lg8, lgp8 (fp8) + xb dump
  mlp_mfma_k<<<(Mn+31)/32, 256, 0, stream>>>(x, w1t, b1, w2t, b2, w3t, b3, Pt,
                                             lg8, lgp8, xb, Mn);
  // 4) ew: 4-edge-batched groups over CSR slots + stats; degnorm+dinv; final weights
  ew2_k<<<1024, 256, 0, stream>>>(lg8, lgp8, csr_src, csr_dst, csr_w, scal, E);
  finalize_k<<<1, 1, 0, stream>>>(scal, E);
  degnorm_k<<<(Mn+255)/256, 256, 0, stream>>>(csr_w, off, scal, dinv, Mn);
  wfin_k<<<(E+255)/256, 256, 0, stream>>>(csr_w, csr_src, csr_dst, dinv, E);
  // 5) x0 = relu(xb@lin0wt + lin0b) -> bufAb (bf16, MFMA)
  bgemm_k<2,true,false,true><<<nGB, 256, 0, stream>>>(xb, lin0wt, lin0b, nullptr, nullptr, bufAb, Mn, 0.f);
  // 6) layer 0: gather agg (bf16) from bufAb; hnext -> bufCb (bf16, MFMA resid)
  agg_gather_k<<<(Mn+3)/4, 256, 0, stream>>>(bufAb, off, csr_src, csr_w, dinv, aggb, Mn);
  bgemm_k<2,true,true,true><<<nGB, 256, 0, stream>>>(aggb, cw1t0, nullptr, aggb, nullptr, bufCb, Mn, beta0);
  // 7) layer 1: gather agg from bufCb; hnext -> bufBb (bf16, MFMA resid)
  agg_gather_k<<<(Mn+3)/4, 256, 0, stream>>>(bufCb, off, csr_src, csr_w, dinv, aggb, Mn);
  bgemm_k<2,true,true,true><<<nGB, 256, 0, stream>>>(aggb, cw1t1, nullptr, aggb, nullptr, bufBb, Mn, beta1);
  // 8) out = bufBb @ lin1wt + lin1b (fp32 out, MFMA)
  bgemm_k<1,false,false,false><<<nGB, 256, 0, stream>>>(bufBb, lin1wt, lin1b, nullptr, out, nullptr, Mn, 0.f);
}